// Round 2
// baseline (2874.454 us; speedup 1.0000x reference)
//
#include <hip/hip_runtime.h>
#include <hip/hip_bf16.h>
#include <stdint.h>

#define N_TOK 2048
#define DMODEL 1024
#define NHEAD 16
#define HDK 64
#define TOPK_K 128

// ---------------- wave helpers ----------------
__device__ __forceinline__ float wave_reduce_max(float v) {
#pragma unroll
  for (int d = 32; d >= 1; d >>= 1) v = fmaxf(v, __shfl_xor(v, d));
  return v;
}
__device__ __forceinline__ float wave_reduce_sum(float v) {
#pragma unroll
  for (int d = 32; d >= 1; d >>= 1) v += __shfl_xor(v, d);
  return v;
}
// order-preserving float->uint key (ascending float -> ascending uint)
__device__ __forceinline__ unsigned f2key(float f) {
  unsigned u = __float_as_uint(f);
  return (u & 0x80000000u) ? ~u : (u | 0x80000000u);
}

// ---------------- LayerNorm ----------------
__global__ __launch_bounds__(256) void ln_kernel(const float* __restrict__ x,
                                                 const float* __restrict__ gamma,
                                                 const float* __restrict__ beta,
                                                 float* __restrict__ xn) {
  int w = threadIdx.x >> 6, lane = threadIdx.x & 63;
  int row = blockIdx.x * 4 + w;
  const float4* xr = (const float4*)(x + (size_t)row * DMODEL);
  float4 v[4];
  float s = 0.f, ss = 0.f;
#pragma unroll
  for (int i = 0; i < 4; ++i) {
    v[i] = xr[i * 64 + lane];
    s += v[i].x + v[i].y + v[i].z + v[i].w;
    ss += v[i].x * v[i].x + v[i].y * v[i].y + v[i].z * v[i].z + v[i].w * v[i].w;
  }
  s = wave_reduce_sum(s);
  ss = wave_reduce_sum(ss);
  float mu = s * (1.f / DMODEL);
  float var = ss * (1.f / DMODEL) - mu * mu;
  float rstd = rsqrtf(var + 1e-5f);
  const float4* g4 = (const float4*)gamma;
  const float4* b4 = (const float4*)beta;
  float4* xo = (float4*)(xn + (size_t)row * DMODEL);
#pragma unroll
  for (int i = 0; i < 4; ++i) {
    float4 g = g4[i * 64 + lane], b = b4[i * 64 + lane], o;
    o.x = (v[i].x - mu) * rstd * g.x + b.x;
    o.y = (v[i].y - mu) * rstd * g.y + b.y;
    o.z = (v[i].z - mu) * rstd * g.z + b.z;
    o.w = (v[i].w - mu) * rstd * g.w + b.w;
    xo[i * 64 + lane] = o;
  }
}

// ---------------- GEMM C = scale*(A . B^T) [+bias] [+res], 64x64 tile ----------------
__global__ __launch_bounds__(256) void gemm_nt_kernel(
    const float* __restrict__ A, int lda, int az,
    const float* __restrict__ B, int ldb, int bz,
    float* __restrict__ C, int ldc, int cz,
    int K, float scale,
    const float* __restrict__ bias,
    const float* __restrict__ res) {
  __shared__ float As[16][68];
  __shared__ float Bs[16][68];
  A += (size_t)blockIdx.z * az;
  B += (size_t)blockIdx.z * bz;
  C += (size_t)blockIdx.z * cz;
  int bi = blockIdx.y * 64, bj = blockIdx.x * 64;
  int tid = threadIdx.x;
  int tx = tid & 15, ty = tid >> 4;
  int lrow = tid >> 2, lcol = (tid & 3) << 2;
  float acc[4][4] = {};
  for (int k0 = 0; k0 < K; k0 += 16) {
    float4 a4 = *(const float4*)(A + (size_t)(bi + lrow) * lda + k0 + lcol);
    float4 b4 = *(const float4*)(B + (size_t)(bj + lrow) * ldb + k0 + lcol);
    As[lcol + 0][lrow] = a4.x; As[lcol + 1][lrow] = a4.y;
    As[lcol + 2][lrow] = a4.z; As[lcol + 3][lrow] = a4.w;
    Bs[lcol + 0][lrow] = b4.x; Bs[lcol + 1][lrow] = b4.y;
    Bs[lcol + 2][lrow] = b4.z; Bs[lcol + 3][lrow] = b4.w;
    __syncthreads();
#pragma unroll
    for (int k = 0; k < 16; ++k) {
      const float4 av = *(const float4*)&As[k][ty << 2];
      const float4 bv = *(const float4*)&Bs[k][tx << 2];
      float ar[4] = {av.x, av.y, av.z, av.w};
      float br[4] = {bv.x, bv.y, bv.z, bv.w};
#pragma unroll
      for (int i = 0; i < 4; ++i)
#pragma unroll
        for (int j = 0; j < 4; ++j) acc[i][j] = fmaf(ar[i], br[j], acc[i][j]);
    }
    __syncthreads();
  }
#pragma unroll
  for (int i = 0; i < 4; ++i) {
    int r = bi + (ty << 2) + i, c = bj + (tx << 2);
    size_t off = (size_t)r * ldc + c;
    float o[4];
#pragma unroll
    for (int j = 0; j < 4; ++j) o[j] = acc[i][j] * scale;
    if (bias) {
#pragma unroll
      for (int j = 0; j < 4; ++j) o[j] += bias[c + j];
    }
    if (res) {
      const float4 rv = *(const float4*)(res + off);
      o[0] += rv.x; o[1] += rv.y; o[2] += rv.z; o[3] += rv.w;
    }
    float4 ov = {o[0], o[1], o[2], o[3]};
    *(float4*)(C + off) = ov;
  }
}

// ---------------- GEMM C = A . B (NN) ----------------
__global__ __launch_bounds__(256) void gemm_nn_kernel(
    const float* __restrict__ A, int lda, int az,
    const float* __restrict__ B, int ldb, int bz,
    float* __restrict__ C, int ldc, int cz,
    int K) {
  __shared__ float As[16][68];
  __shared__ float Bs[16][68];
  A += (size_t)blockIdx.z * az;
  B += (size_t)blockIdx.z * bz;
  C += (size_t)blockIdx.z * cz;
  int bi = blockIdx.y * 64, bj = blockIdx.x * 64;
  int tid = threadIdx.x;
  int tx = tid & 15, ty = tid >> 4;
  int lrow = tid >> 2, lcol = (tid & 3) << 2;  // A loader: 64 rows x 16 k
  int brow = tid >> 4, bcol = (tid & 15) << 2; // B loader: 16 k x 64 cols
  float acc[4][4] = {};
  for (int k0 = 0; k0 < K; k0 += 16) {
    float4 a4 = *(const float4*)(A + (size_t)(bi + lrow) * lda + k0 + lcol);
    float4 b4 = *(const float4*)(B + (size_t)(k0 + brow) * ldb + bj + bcol);
    As[lcol + 0][lrow] = a4.x; As[lcol + 1][lrow] = a4.y;
    As[lcol + 2][lrow] = a4.z; As[lcol + 3][lrow] = a4.w;
    *(float4*)&Bs[brow][bcol] = b4;
    __syncthreads();
#pragma unroll
    for (int k = 0; k < 16; ++k) {
      const float4 av = *(const float4*)&As[k][ty << 2];
      const float4 bv = *(const float4*)&Bs[k][tx << 2];
      float ar[4] = {av.x, av.y, av.z, av.w};
      float br[4] = {bv.x, bv.y, bv.z, bv.w};
#pragma unroll
      for (int i = 0; i < 4; ++i)
#pragma unroll
        for (int j = 0; j < 4; ++j) acc[i][j] = fmaf(ar[i], br[j], acc[i][j]);
    }
    __syncthreads();
  }
#pragma unroll
  for (int i = 0; i < 4; ++i) {
    size_t off = (size_t)(bi + (ty << 2) + i) * ldc + bj + (tx << 2);
    float4 ov = {acc[i][0], acc[i][1], acc[i][2], acc[i][3]};
    *(float4*)(C + off) = ov;
  }
}

// ---------------- Fused: pre-mix -> softmax -> exact top-k -> renorm -> post-mix ----------------
// One block per query q (within chunk). S layout: (q, h, k), 16x2048 fp32 per q in LDS.
__global__ __launch_bounds__(1024) void fused_rows_kernel(
    float* __restrict__ S,
    const float* __restrict__ Wpre, const float* __restrict__ Wpost,
    const float* __restrict__ bpost) {
  __shared__ float row[NHEAD][N_TOK];     // 128 KB
  __shared__ unsigned hist[NHEAD][258];
  __shared__ float wpre_s[256], wpost_s[256], bpost_s[16];
  int tid = threadIdx.x;
  size_t qbase = (size_t)blockIdx.x * (NHEAD * N_TOK);
  if (tid < 256) { wpre_s[tid] = Wpre[tid]; wpost_s[tid] = Wpost[tid]; }
  if (tid >= 256 && tid < 272) bpost_s[tid - 256] = bpost[tid - 256];
  float* rflat = &row[0][0];
  const float4* gS = (const float4*)(S + qbase);
#pragma unroll
  for (int i = 0; i < 8; ++i) ((float4*)rflat)[i * 1024 + tid] = gS[i * 1024 + tid];
  __syncthreads();

  // pre talking-heads mix, in place per column
#pragma unroll
  for (int c0 = 0; c0 < N_TOK; c0 += 1024) {
    int c = c0 + tid;
    float sv[16], mv[16];
#pragma unroll
    for (int h = 0; h < 16; ++h) sv[h] = row[h][c];
#pragma unroll
    for (int g = 0; g < 16; ++g) {
      float a = 0.f;
#pragma unroll
      for (int h = 0; h < 16; ++h) a = fmaf(wpre_s[g * 16 + h], sv[h], a);
      mv[g] = a;
    }
#pragma unroll
    for (int g = 0; g < 16; ++g) row[g][c] = mv[g];
  }
  __syncthreads();

  int w = tid >> 6, lane = tid & 63;
  float v[32];
#pragma unroll
  for (int j = 0; j < 32; ++j) v[j] = row[w][lane + (j << 6)];

  // softmax stats (dense)
  float mx = v[0];
#pragma unroll
  for (int j = 1; j < 32; ++j) mx = fmaxf(mx, v[j]);
  mx = wave_reduce_max(mx);
  float z = 0.f;
#pragma unroll
  for (int j = 0; j < 32; ++j) z += __expf(v[j] - mx);
  z = wave_reduce_sum(z);

  // exact 128th-largest via 4-pass radix select (wave-private hist)
  unsigned prefix = 0;
  int remaining = TOPK_K;
  unsigned* hw = hist[w];
#pragma unroll 1
  for (int pass = 0; pass < 4; ++pass) {
    int shift = 24 - (pass << 3);
    for (int b = lane; b < 256; b += 64) hw[b] = 0;
    __syncthreads();
#pragma unroll
    for (int j = 0; j < 32; ++j) {
      unsigned k = f2key(v[j]);
      bool in = (pass == 0) || ((k >> (shift + 8)) == (prefix >> (shift + 8)));
      if (in) atomicAdd(&hw[(k >> shift) & 255], 1u);
    }
    __syncthreads();
    unsigned hh[4];
#pragma unroll
    for (int b = 0; b < 4; ++b) hh[b] = hw[(lane << 2) + b];
    unsigned csum = hh[0] + hh[1] + hh[2] + hh[3];
    unsigned suf = csum;
#pragma unroll
    for (int d = 1; d < 64; d <<= 1) {
      unsigned o = __shfl_down(suf, d);
      if (lane + d < 64) suf += o;
    }
    unsigned above = suf - csum;  // count with digit >= 4*(lane+1)
    int fdig = -1, frem = 0;
    unsigned cum = above;
#pragma unroll
    for (int b = 3; b >= 0; --b) {
      if (fdig < 0 && cum + hh[b] >= (unsigned)remaining) {
        fdig = (lane << 2) + b;
        frem = remaining - (int)cum;
      } else if (fdig < 0) {
        cum += hh[b];
      }
    }
    unsigned long long ball = __ballot(fdig >= 0);
    // firing lanes are 0..L*, the threshold digit lives in the HIGHEST one
    int src = 63 - (int)__clzll(ball);
    int dig = __shfl(fdig, src);
    remaining = __shfl(frem, src);
    prefix |= ((unsigned)dig) << shift;
    __syncthreads();
  }

  // masked sum + sparse renorm write-back (mask: key >= prefix  <=>  attn >= kth)
  float invZ = 1.f / z;
  float msum = 0.f;
  unsigned keep = 0;
#pragma unroll
  for (int j = 0; j < 32; ++j) {
    unsigned k = f2key(v[j]);
    float p = __expf(v[j] - mx) * invZ;
    if (k >= prefix) { msum += p; keep |= (1u << j); }
    v[j] = p;
  }
  msum = wave_reduce_sum(msum);
  float invDen = 1.f / (msum + 1e-9f);
#pragma unroll
  for (int j = 0; j < 32; ++j)
    row[w][lane + (j << 6)] = ((keep >> j) & 1u) ? v[j] * invDen : 0.f;
  __syncthreads();

  // post talking-heads mix (+bpost, dense) -> write attn2 in place over S
  float* gout = S + qbase;
#pragma unroll
  for (int c0 = 0; c0 < N_TOK; c0 += 1024) {
    int c = c0 + tid;
    float sv[16];
#pragma unroll
    for (int h = 0; h < 16; ++h) sv[h] = row[h][c];
#pragma unroll
    for (int g = 0; g < 16; ++g) {
      float a = bpost_s[g];
#pragma unroll
      for (int h = 0; h < 16; ++h) a = fmaf(wpost_s[g * 16 + h], sv[h], a);
      gout[g * N_TOK + c] = a;
    }
  }
}

// ---------------- launch ----------------
extern "C" void kernel_launch(void* const* d_in, const int* in_sizes, int n_in,
                              void* d_out, int out_size, void* d_ws, size_t ws_size,
                              hipStream_t stream) {
  const float* x     = (const float*)d_in[0];
  const float* Wq    = (const float*)d_in[1];
  const float* bq    = (const float*)d_in[2];
  const float* Wk    = (const float*)d_in[3];
  const float* bk    = (const float*)d_in[4];
  const float* Wv    = (const float*)d_in[5];
  const float* bv    = (const float*)d_in[6];
  const float* Wpre  = (const float*)d_in[7];
  // d_in[8] = bpre: no-op (constant per softmax row; softmax shift-invariant; topk order unchanged)
  const float* Wpost = (const float*)d_in[9];
  const float* bpost = (const float*)d_in[10];
  const float* Wo    = (const float*)d_in[11];
  const float* bo    = (const float*)d_in[12];
  const float* gamma = (const float*)d_in[13];
  const float* beta  = (const float*)d_in[14];
  float* out = (float*)d_out;

  float* ws = (float*)d_ws;
  const size_t NM = (size_t)N_TOK * DMODEL;  // 2M elems
  // xn is dead after the projections -> alias AO onto it.
  float* xn = ws;
  float* AO = ws;
  float* Q  = ws + NM;
  float* Kp = ws + 2 * NM;
  float* V  = ws + 3 * NM;
  float* S  = ws + 4 * NM;  // chunk buffer: CQ x 16 x 2048 fp32, reused per chunk

  // adaptive q-chunking so we fit whatever ws_size the harness gives us
  const size_t base_bytes = 4 * NM * sizeof(float);
  int CQ = 0;
  const int cands[6] = {2048, 1024, 512, 256, 128, 64};
  for (int i = 0; i < 6; ++i) {
    size_t need = base_bytes + (size_t)cands[i] * NHEAD * N_TOK * sizeof(float);
    if (need <= ws_size) { CQ = cands[i]; break; }
  }
  if (CQ == 0) return;  // cannot run safely

  ln_kernel<<<N_TOK / 4, 256, 0, stream>>>(x, gamma, beta, xn);

  // Q/K/V projections: xn @ W^T + b
  gemm_nt_kernel<<<dim3(16, 32, 1), 256, 0, stream>>>(xn, DMODEL, 0, Wq, DMODEL, 0,
                                                      Q, DMODEL, 0, DMODEL, 1.f, bq, nullptr);
  gemm_nt_kernel<<<dim3(16, 32, 1), 256, 0, stream>>>(xn, DMODEL, 0, Wk, DMODEL, 0,
                                                      Kp, DMODEL, 0, DMODEL, 1.f, bk, nullptr);
  gemm_nt_kernel<<<dim3(16, 32, 1), 256, 0, stream>>>(xn, DMODEL, 0, Wv, DMODEL, 0,
                                                      V, DMODEL, 0, DMODEL, 1.f, bv, nullptr);

  for (int q0 = 0; q0 < N_TOK; q0 += CQ) {
    // scores chunk: S[ql][h][k] = (Q_h[q0+ql] . K_h^T) / 8
    gemm_nt_kernel<<<dim3(N_TOK / 64, CQ / 64, NHEAD), 256, 0, stream>>>(
        Q + (size_t)q0 * DMODEL, DMODEL, HDK, Kp, DMODEL, HDK,
        S, NHEAD * N_TOK, N_TOK, HDK, 0.125f, nullptr, nullptr);

    // fused talking-heads pipeline, one block per query in chunk
    fused_rows_kernel<<<CQ, 1024, 0, stream>>>(S, Wpre, Wpost, bpost);

    // PV chunk: AO[q0+ql][h*64+d] = sum_k attn2[ql][h][k] * V[k][h*64+d]
    gemm_nn_kernel<<<dim3(1, CQ / 64, NHEAD), 256, 0, stream>>>(
        S, NHEAD * N_TOK, N_TOK, V, DMODEL, HDK,
        AO + (size_t)q0 * DMODEL, DMODEL, HDK, N_TOK);
  }

  // out = AO @ Wo^T + bo + x
  gemm_nt_kernel<<<dim3(16, 32, 1), 256, 0, stream>>>(AO, DMODEL, 0, Wo, DMODEL, 0,
                                                      out, DMODEL, 0, DMODEL, 1.f, bo, x);
}

// Round 5
// 2279.388 us; speedup vs baseline: 1.2611x; 1.2611x over previous
//
#include <hip/hip_runtime.h>
#include <stdint.h>

typedef unsigned short u16;
using bf16x8 = __attribute__((ext_vector_type(8))) short;
using f32x4  = __attribute__((ext_vector_type(4))) float;

#define N_TOK 2048
#define DMODEL 1024
#define NHEAD 16
#define HDK 64
#define TOPK_K 128

// ---------------- numeric helpers ----------------
__device__ __forceinline__ u16 f2b(float f) {  // fp32 -> bf16 RNE
  unsigned u = __float_as_uint(f);
  return (u16)((u + 0x7FFFu + ((u >> 16) & 1u)) >> 16);
}
__device__ __forceinline__ float b2f(u16 b) {
  return __uint_as_float(((unsigned)b) << 16);
}
__device__ __forceinline__ float wave_reduce_max(float v) {
#pragma unroll
  for (int d = 32; d >= 1; d >>= 1) v = fmaxf(v, __shfl_xor(v, d));
  return v;
}
__device__ __forceinline__ float wave_reduce_sum(float v) {
#pragma unroll
  for (int d = 32; d >= 1; d >>= 1) v += __shfl_xor(v, d);
  return v;
}
__device__ __forceinline__ unsigned f2key(float f) {  // order-preserving
  unsigned u = __float_as_uint(f);
  return (u & 0x80000000u) ? ~u : (u | 0x80000000u);
}

// ---------------- LayerNorm -> bf16 ----------------
__global__ __launch_bounds__(256) void ln_kernel(const float* __restrict__ x,
                                                 const float* __restrict__ gamma,
                                                 const float* __restrict__ beta,
                                                 u16* __restrict__ xn) {
  int w = threadIdx.x >> 6, lane = threadIdx.x & 63;
  int row = blockIdx.x * 4 + w;
  const float4* xr = (const float4*)(x + (size_t)row * DMODEL);
  float4 v[4];
  float s = 0.f, ss = 0.f;
#pragma unroll
  for (int i = 0; i < 4; ++i) {
    v[i] = xr[i * 64 + lane];
    s += v[i].x + v[i].y + v[i].z + v[i].w;
    ss += v[i].x * v[i].x + v[i].y * v[i].y + v[i].z * v[i].z + v[i].w * v[i].w;
  }
  s = wave_reduce_sum(s);
  ss = wave_reduce_sum(ss);
  float mu = s * (1.f / DMODEL);
  float var = ss * (1.f / DMODEL) - mu * mu;
  float rstd = rsqrtf(var + 1e-5f);
  const float4* g4 = (const float4*)gamma;
  const float4* b4 = (const float4*)beta;
  u16* xo = xn + (size_t)row * DMODEL;
#pragma unroll
  for (int i = 0; i < 4; ++i) {
    float4 g = g4[i * 64 + lane], b = b4[i * 64 + lane];
    float ox = (v[i].x - mu) * rstd * g.x + b.x;
    float oy = (v[i].y - mu) * rstd * g.y + b.y;
    float oz = (v[i].z - mu) * rstd * g.z + b.z;
    float ow = (v[i].w - mu) * rstd * g.w + b.w;
    unsigned lo = (unsigned)f2b(ox) | ((unsigned)f2b(oy) << 16);
    unsigned hi = (unsigned)f2b(oz) | ((unsigned)f2b(ow) << 16);
    *(uint2*)&xo[(i * 64 + lane) * 4] = make_uint2(lo, hi);
  }
}

// ---------------- fp32 -> bf16 cast (n8 = elems/8) ----------------
__global__ __launch_bounds__(256) void cast_kernel(const float* __restrict__ in,
                                                   u16* __restrict__ out, int n8) {
  int i = blockIdx.x * 256 + threadIdx.x;
  if (i >= n8) return;
  const float4* p = (const float4*)in + (size_t)i * 2;
  float4 a = p[0], b = p[1];
  unsigned w0 = (unsigned)f2b(a.x) | ((unsigned)f2b(a.y) << 16);
  unsigned w1 = (unsigned)f2b(a.z) | ((unsigned)f2b(a.w) << 16);
  unsigned w2 = (unsigned)f2b(b.x) | ((unsigned)f2b(b.y) << 16);
  unsigned w3 = (unsigned)f2b(b.z) | ((unsigned)f2b(b.w) << 16);
  *(uint4*)&out[(size_t)i * 8] = make_uint4(w0, w1, w2, w3);
}

// ---------------- V (2048x1024) -> Vt (1024x2048) bf16 transpose ----------------
__global__ __launch_bounds__(256) void transpose_kernel(const u16* __restrict__ V,
                                                        u16* __restrict__ Vt) {
  __shared__ u16 tile[64][72];
  int kb = blockIdx.x * 64, cb = blockIdx.y * 64;
  int t = threadIdx.x;
  int r = t >> 2, cg = (t & 3) * 16;
  *(uint4*)&tile[r][cg]     = *(const uint4*)&V[(size_t)(kb + r) * DMODEL + cb + cg];
  *(uint4*)&tile[r][cg + 8] = *(const uint4*)&V[(size_t)(kb + r) * DMODEL + cb + cg + 8];
  __syncthreads();
  int c = t >> 2, kg = (t & 3) * 16;
  size_t base = (size_t)(cb + c) * N_TOK + kb + kg;
  unsigned p0 = (unsigned)tile[kg + 0][c] | ((unsigned)tile[kg + 1][c] << 16);
  unsigned p1 = (unsigned)tile[kg + 2][c] | ((unsigned)tile[kg + 3][c] << 16);
  unsigned p2 = (unsigned)tile[kg + 4][c] | ((unsigned)tile[kg + 5][c] << 16);
  unsigned p3 = (unsigned)tile[kg + 6][c] | ((unsigned)tile[kg + 7][c] << 16);
  unsigned p4 = (unsigned)tile[kg + 8][c] | ((unsigned)tile[kg + 9][c] << 16);
  unsigned p5 = (unsigned)tile[kg + 10][c] | ((unsigned)tile[kg + 11][c] << 16);
  unsigned p6 = (unsigned)tile[kg + 12][c] | ((unsigned)tile[kg + 13][c] << 16);
  unsigned p7 = (unsigned)tile[kg + 14][c] | ((unsigned)tile[kg + 15][c] << 16);
  *(uint4*)&Vt[base]     = make_uint4(p0, p1, p2, p3);
  *(uint4*)&Vt[base + 8] = make_uint4(p4, p5, p6, p7);
}

// ---------------- bf16 MFMA GEMM: C = scale*(A . B^T) [+bias] [+res] ----------------
// A: (M x K) bf16 rows lda; B: (N x K) bf16 rows ldb. Per-z elem offsets az/bz/cz.
// out_f32 ? C fp32 : C bf16. Grid (N/64, M/64, Z), block 256 (4 waves, 2x2 frags).
__global__ __launch_bounds__(256) void gemm_bf16_nt(
    const u16* __restrict__ A, int lda, int az,
    const u16* __restrict__ B, int ldb, int bz,
    void* __restrict__ Cv, int ldc, int cz,
    int K, float scale,
    const float* __restrict__ bias,
    const float* __restrict__ res, int out_f32) {
  __shared__ u16 As[64 * 40];  // row stride 40 bf16 (80 B): 16B-aligned, 2-way max
  __shared__ u16 Bs[64 * 40];
  A += (size_t)blockIdx.z * az;
  B += (size_t)blockIdx.z * bz;
  int bi = blockIdx.y * 64, bj = blockIdx.x * 64;
  int tid = threadIdx.x;
  int w = tid >> 6, lane = tid & 63;
  int wr = w >> 1, wc = w & 1;
  int lr = tid >> 2, lc = (tid & 3) * 8;
  int kh = (lane >> 4) * 8, fr = lane & 15;
  f32x4 acc[2][2] = {};
  for (int k0 = 0; k0 < K; k0 += 32) {
    *(uint4*)&As[lr * 40 + lc] = *(const uint4*)&A[(size_t)(bi + lr) * lda + k0 + lc];
    *(uint4*)&Bs[lr * 40 + lc] = *(const uint4*)&B[(size_t)(bj + lr) * ldb + k0 + lc];
    __syncthreads();
    bf16x8 a0 = *(bf16x8*)&As[(wr * 32 + fr) * 40 + kh];
    bf16x8 a1 = *(bf16x8*)&As[(wr * 32 + 16 + fr) * 40 + kh];
    bf16x8 b0 = *(bf16x8*)&Bs[(wc * 32 + fr) * 40 + kh];
    bf16x8 b1 = *(bf16x8*)&Bs[(wc * 32 + 16 + fr) * 40 + kh];
    acc[0][0] = __builtin_amdgcn_mfma_f32_16x16x32_bf16(a0, b0, acc[0][0], 0, 0, 0);
    acc[0][1] = __builtin_amdgcn_mfma_f32_16x16x32_bf16(a0, b1, acc[0][1], 0, 0, 0);
    acc[1][0] = __builtin_amdgcn_mfma_f32_16x16x32_bf16(a1, b0, acc[1][0], 0, 0, 0);
    acc[1][1] = __builtin_amdgcn_mfma_f32_16x16x32_bf16(a1, b1, acc[1][1], 0, 0, 0);
    __syncthreads();
  }
  float* Cf = (float*)Cv + (size_t)blockIdx.z * cz;
  u16* Ch = (u16*)Cv + (size_t)blockIdx.z * cz;
  int rg = (lane >> 4) * 4;
#pragma unroll
  for (int m = 0; m < 2; ++m) {
#pragma unroll
    for (int n = 0; n < 2; ++n) {
      int gcol = bj + wc * 32 + n * 16 + fr;
      float badd = bias ? bias[gcol] : 0.f;
#pragma unroll
      for (int r = 0; r < 4; ++r) {
        int grow = bi + wr * 32 + m * 16 + rg + r;
        size_t off = (size_t)grow * ldc + gcol;
        float v = acc[m][n][r] * scale + badd;
        if (res) v += res[off];
        if (out_f32) Cf[off] = v;
        else Ch[off] = f2b(v);
      }
    }
  }
}

// ---------------- Fused: pre-mix -> softmax -> exact top-k -> renorm -> post-mix ----
// One block per query. S (bf16) layout (q, h, k); fp32 internals in LDS.
__global__ __launch_bounds__(1024, 4) void fused_rows_kernel(
    u16* __restrict__ S,
    const float* __restrict__ Wpre, const float* __restrict__ Wpost,
    const float* __restrict__ bpost) {
  __shared__ float row[NHEAD][N_TOK];   // 128 KB
  __shared__ unsigned hist[NHEAD][258];
  __shared__ float wpre_s[256], wpost_s[256], bpost_s[16];
  int tid = threadIdx.x;
  size_t qbase = (size_t)blockIdx.x * (NHEAD * N_TOK);
  if (tid < 256) { wpre_s[tid] = Wpre[tid]; wpost_s[tid] = Wpost[tid]; }
  if (tid >= 256 && tid < 272) bpost_s[tid - 256] = bpost[tid - 256];
  const u16* gS = S + qbase;
  float* rflat = &row[0][0];
#pragma unroll
  for (int i = 0; i < 4; ++i) {
    int e0 = (i * 1024 + tid) * 8;
    uint4 pk = *(const uint4*)&gS[e0];
    rflat[e0 + 0] = __uint_as_float(pk.x << 16);
    rflat[e0 + 1] = __uint_as_float(pk.x & 0xFFFF0000u);
    rflat[e0 + 2] = __uint_as_float(pk.y << 16);
    rflat[e0 + 3] = __uint_as_float(pk.y & 0xFFFF0000u);
    rflat[e0 + 4] = __uint_as_float(pk.z << 16);
    rflat[e0 + 5] = __uint_as_float(pk.z & 0xFFFF0000u);
    rflat[e0 + 6] = __uint_as_float(pk.w << 16);
    rflat[e0 + 7] = __uint_as_float(pk.w & 0xFFFF0000u);
  }
  __syncthreads();

  // pre talking-heads mix, in place per column (thread owns its columns)
#pragma unroll
  for (int c0 = 0; c0 < N_TOK; c0 += 1024) {
    int c = c0 + tid;
    float sv[16], mv[16];
#pragma unroll
    for (int h = 0; h < 16; ++h) sv[h] = row[h][c];
#pragma unroll
    for (int g = 0; g < 16; ++g) {
      float a = 0.f;
#pragma unroll
      for (int h = 0; h < 16; ++h) a = fmaf(wpre_s[g * 16 + h], sv[h], a);
      mv[g] = a;
    }
#pragma unroll
    for (int g = 0; g < 16; ++g) row[g][c] = mv[g];
  }
  __syncthreads();

  int w = tid >> 6, lane = tid & 63;
  float v[32];
#pragma unroll
  for (int j = 0; j < 32; ++j) v[j] = row[w][lane + (j << 6)];

  float mx = v[0];
#pragma unroll
  for (int j = 1; j < 32; ++j) mx = fmaxf(mx, v[j]);
  mx = wave_reduce_max(mx);
  float z = 0.f;
#pragma unroll
  for (int j = 0; j < 32; ++j) z += __expf(v[j] - mx);
  z = wave_reduce_sum(z);

  // exact 128th-largest via 4-pass radix select (wave-private hist)
  unsigned prefix = 0;
  int remaining = TOPK_K;
  unsigned* hw = hist[w];
#pragma unroll 1
  for (int pass = 0; pass < 4; ++pass) {
    int shift = 24 - (pass << 3);
    for (int b = lane; b < 256; b += 64) hw[b] = 0;
    __syncthreads();
#pragma unroll
    for (int j = 0; j < 32; ++j) {
      unsigned k = f2key(v[j]);
      bool in = (pass == 0) || ((k >> (shift + 8)) == (prefix >> (shift + 8)));
      if (in) atomicAdd(&hw[(k >> shift) & 255], 1u);
    }
    __syncthreads();
    unsigned hh[4];
#pragma unroll
    for (int b = 0; b < 4; ++b) hh[b] = hw[(lane << 2) + b];
    unsigned csum = hh[0] + hh[1] + hh[2] + hh[3];
    unsigned suf = csum;
#pragma unroll
    for (int d = 1; d < 64; d <<= 1) {
      unsigned o = __shfl_down(suf, d);
      if (lane + d < 64) suf += o;
    }
    unsigned above = suf - csum;
    int fdig = -1, frem = 0;
    unsigned cum = above;
#pragma unroll
    for (int b = 3; b >= 0; --b) {
      if (fdig < 0 && cum + hh[b] >= (unsigned)remaining) {
        fdig = (lane << 2) + b;
        frem = remaining - (int)cum;
      } else if (fdig < 0) {
        cum += hh[b];
      }
    }
    unsigned long long ball = __ballot(fdig >= 0);
    int src = 63 - (int)__clzll(ball);  // threshold digit is in the HIGHEST firing lane
    int dig = __shfl(fdig, src);
    remaining = __shfl(frem, src);
    prefix |= ((unsigned)dig) << shift;
    __syncthreads();
  }

  // masked sum + sparse renorm (mask: key >= prefix  <=>  attn >= kth, ties kept)
  float invZ = 1.f / z;
  float msum = 0.f;
  unsigned keep = 0;
#pragma unroll
  for (int j = 0; j < 32; ++j) {
    unsigned k = f2key(v[j]);
    float p = __expf(v[j] - mx) * invZ;
    if (k >= prefix) { msum += p; keep |= (1u << j); }
    v[j] = p;
  }
  msum = wave_reduce_sum(msum);
  float invDen = 1.f / (msum + 1e-9f);
#pragma unroll
  for (int j = 0; j < 32; ++j)
    row[w][lane + (j << 6)] = ((keep >> j) & 1u) ? v[j] * invDen : 0.f;
  __syncthreads();

  // post talking-heads mix (+bpost) -> bf16 attn2 in place over S
  u16* gout = S + qbase;
#pragma unroll
  for (int c0 = 0; c0 < N_TOK; c0 += 1024) {
    int c = c0 + tid;
    float sv[16];
#pragma unroll
    for (int h = 0; h < 16; ++h) sv[h] = row[h][c];
#pragma unroll
    for (int g = 0; g < 16; ++g) {
      float a = bpost_s[g];
#pragma unroll
      for (int h = 0; h < 16; ++h) a = fmaf(wpost_s[g * 16 + h], sv[h], a);
      gout[g * N_TOK + c] = f2b(a);
    }
  }
}

// ---------------- launch ----------------
extern "C" void kernel_launch(void* const* d_in, const int* in_sizes, int n_in,
                              void* d_out, int out_size, void* d_ws, size_t ws_size,
                              hipStream_t stream) {
  const float* x     = (const float*)d_in[0];
  const float* Wq    = (const float*)d_in[1];
  const float* bq    = (const float*)d_in[2];
  const float* Wk    = (const float*)d_in[3];
  const float* bk    = (const float*)d_in[4];
  const float* Wv    = (const float*)d_in[5];
  const float* bv    = (const float*)d_in[6];
  const float* Wpre  = (const float*)d_in[7];
  // d_in[8] = bpre: no-op (softmax shift-invariant; top-k order unchanged)
  const float* Wpost = (const float*)d_in[9];
  const float* bpost = (const float*)d_in[10];
  const float* Wo    = (const float*)d_in[11];
  const float* bo    = (const float*)d_in[12];
  const float* gamma = (const float*)d_in[13];
  const float* beta  = (const float*)d_in[14];

  const size_t NM = (size_t)N_TOK * DMODEL;   // 2M
  const size_t WW = (size_t)DMODEL * DMODEL;  // 1M
  char* p = (char*)d_ws;
  u16* xnb = (u16*)p; p += NM * 2;
  u16* Qb  = (u16*)p; p += NM * 2;
  u16* Kb  = (u16*)p; p += NM * 2;
  u16* Vb  = (u16*)p; p += NM * 2;
  u16* Vtb = (u16*)p; p += NM * 2;
  u16* AOb = (u16*)p; p += NM * 2;
  u16* Wqb = (u16*)p; p += WW * 2;
  u16* Wkb = (u16*)p; p += WW * 2;
  u16* Wvb = (u16*)p; p += WW * 2;
  u16* Wob = (u16*)p; p += WW * 2;
  u16* S   = (u16*)p;
  size_t base = (size_t)(p - (char*)d_ws);

  int CQ = 0;
  const int cands[6] = {2048, 1024, 512, 256, 128, 64};
  for (int i = 0; i < 6; ++i) {
    if (base + (size_t)cands[i] * NHEAD * N_TOK * 2 <= ws_size) { CQ = cands[i]; break; }
  }
  if (CQ == 0) return;

  ln_kernel<<<N_TOK / 4, 256, 0, stream>>>(x, gamma, beta, xnb);
  cast_kernel<<<512, 256, 0, stream>>>(Wq, Wqb, WW / 8);
  cast_kernel<<<512, 256, 0, stream>>>(Wk, Wkb, WW / 8);
  cast_kernel<<<512, 256, 0, stream>>>(Wv, Wvb, WW / 8);
  cast_kernel<<<512, 256, 0, stream>>>(Wo, Wob, WW / 8);

  gemm_bf16_nt<<<dim3(16, 32, 1), 256, 0, stream>>>(xnb, DMODEL, 0, Wqb, DMODEL, 0,
                                                    Qb, DMODEL, 0, DMODEL, 1.f, bq, nullptr, 0);
  gemm_bf16_nt<<<dim3(16, 32, 1), 256, 0, stream>>>(xnb, DMODEL, 0, Wkb, DMODEL, 0,
                                                    Kb, DMODEL, 0, DMODEL, 1.f, bk, nullptr, 0);
  gemm_bf16_nt<<<dim3(16, 32, 1), 256, 0, stream>>>(xnb, DMODEL, 0, Wvb, DMODEL, 0,
                                                    Vb, DMODEL, 0, DMODEL, 1.f, bv, nullptr, 0);
  transpose_kernel<<<dim3(N_TOK / 64, DMODEL / 64), 256, 0, stream>>>(Vb, Vtb);

  for (int q0 = 0; q0 < N_TOK; q0 += CQ) {
    // scores: S[ql][h][k] = 0.125 * Q_h[q0+ql] . K_h^T   (bf16 out)
    gemm_bf16_nt<<<dim3(N_TOK / 64, CQ / 64, NHEAD), 256, 0, stream>>>(
        Qb + (size_t)q0 * DMODEL, DMODEL, HDK, Kb, DMODEL, HDK,
        S, NHEAD * N_TOK, N_TOK, HDK, 0.125f, nullptr, nullptr, 0);

    fused_rows_kernel<<<CQ, 1024, 0, stream>>>(S, Wpre, Wpost, bpost);

    // PV: AO[q0+ql][h*64+d] = attn2[ql][h][:] . Vt_h[d][:]   (bf16 out)
    gemm_bf16_nt<<<dim3(1, CQ / 64, NHEAD), 256, 0, stream>>>(
        S, NHEAD * N_TOK, N_TOK, Vtb, N_TOK, HDK * N_TOK,
        AOb + (size_t)q0 * DMODEL, DMODEL, HDK, N_TOK, 1.f, nullptr, nullptr, 0);
  }

  // out = AO @ Wo^T + bo + x   (fp32 out)
  gemm_bf16_nt<<<dim3(16, 32, 1), 256, 0, stream>>>(AOb, DMODEL, 0, Wob, DMODEL, 0,
                                                    d_out, DMODEL, 0, DMODEL, 1.f, bo, x, 1);
}